// Round 1
// baseline (6289.327 us; speedup 1.0000x reference)
//
#include <hip/hip_runtime.h>
#include <math.h>

#define PW 160
#define PSQ 25600          // 160*160
#define NB 4
#define NC 3
#define NH 32
#define NX 307200          // NB*NC*PSQ
#define NDIM 76800         // NC*PSQ

struct TS40 { float t[40]; };
struct MC40 { float m[40]; float A; };

// ---------------- time embedding: emb[r][h] = (sin|cos)(t_r*999*freqs) @ wt + bt
__global__ void emb_kernel(const float* __restrict__ wt, const float* __restrict__ bt,
                           float* __restrict__ emb, TS40 ts) {
    int r = blockIdx.x, k = threadIdx.x;   // 64 threads
    __shared__ float e64[64];
    float t = ts.t[r];
    int j = k & 31;
    float freq = expf(-0.29710775393471556f * (float)j);  // -ln(10000)/31
    float a = t * 999.0f * freq;
    e64[k] = (k < 32) ? sinf(a) : cosf(a);
    __syncthreads();
    if (k < 32) {
        float acc = bt[k];
        #pragma unroll 8
        for (int q = 0; q < 64; q++) acc += e64[q] * wt[q * 32 + k];
        emb[r * 32 + k] = acc;
    }
}

// ---------------- weight repack OIHW -> [ci][tap][co] for SGPR-contiguous co reads
__global__ void repack_kernel(const float* __restrict__ src, float* __restrict__ dst,
                              int CO, int CI) {
    int i = blockIdx.x * 256 + threadIdx.x;
    int n = CO * CI * 9;
    if (i >= n) return;
    int co = i / (CI * 9);
    int rem = i - co * CI * 9;
    int ci = rem / 9;
    int t = rem - ci * 9;
    dst[(ci * 9 + t) * CO + co] = src[i];
}

// ---------------- conv1: 3->32. WITH_ACT: out = relu(conv+b1+emb). else raw conv (for teps).
template <bool WITH_ACT>
__global__ __launch_bounds__(256) void conv1_kernel(
    const float* __restrict__ in, const float* __restrict__ w1t,
    const float* __restrict__ b1, const float* __restrict__ emb,
    float* __restrict__ out) {
    const int tile = blockIdx.x;
    const int b = blockIdx.y;
    const int ty0 = (tile / 10) * 16, tx0 = (tile % 10) * 16;
    const int tid = threadIdx.x;
    const int tx = tid & 15, ty = tid >> 4;
    __shared__ float smem[3][18][18];
    for (int idx = tid; idx < 3 * 324; idx += 256) {
        int ci = idx / 324;
        int rem = idx - ci * 324;
        int ly = rem / 18, lx = rem - (rem / 18) * 18;
        int gy = ty0 + ly - 1, gx = tx0 + lx - 1;
        float v = 0.0f;
        if (gy >= 0 && gy < PW && gx >= 0 && gx < PW)
            v = in[((b * 3 + ci) * PW + gy) * PW + gx];
        smem[ci][ly][lx] = v;
    }
    __syncthreads();
    float acc[32];
    #pragma unroll
    for (int k = 0; k < 32; k++) acc[k] = 0.0f;
    #pragma unroll
    for (int ci = 0; ci < 3; ci++) {
        #pragma unroll
        for (int ky = 0; ky < 3; ky++) {
            #pragma unroll
            for (int kx = 0; kx < 3; kx++) {
                float v = smem[ci][ty + ky][tx + kx];
                const float* wp = &w1t[(ci * 9 + ky * 3 + kx) * 32];
                #pragma unroll
                for (int k = 0; k < 32; k++) acc[k] += v * wp[k];
            }
        }
    }
    const int py = ty0 + ty, px = tx0 + tx;
    #pragma unroll
    for (int k = 0; k < 32; k++) {
        float r = acc[k];
        if (WITH_ACT) { r = fmaxf(r + b1[k] + emb[k], 0.0f); }
        out[((b * 32 + k) * PW + py) * PW + px] = r;
    }
}

// ---------------- conv2: 32->32, co split by blockIdx.z (16 per block).
// TANGENT: input = (h1>0)?teps:0 (broadcast teps over batch), output raw (no bias/relu).
template <bool TANGENT>
__global__ __launch_bounds__(256) void conv2_kernel(
    const float* __restrict__ h1, const float* __restrict__ teps,
    const float* __restrict__ w2t, const float* __restrict__ b2,
    float* __restrict__ out) {
    const int tile = blockIdx.x;
    const int b = blockIdx.y;
    const int half = blockIdx.z;  // 0/1 -> co 0..15 / 16..31
    const int ty0 = (tile / 10) * 16, tx0 = (tile % 10) * 16;
    const int tid = threadIdx.x;
    const int tx = tid & 15, ty = tid >> 4;
    __shared__ float smem[4][18][18];
    float acc[16];
    #pragma unroll
    for (int k = 0; k < 16; k++) acc[k] = 0.0f;
    for (int cg = 0; cg < 8; cg++) {
        __syncthreads();
        for (int idx = tid; idx < 4 * 324; idx += 256) {
            int cil = idx / 324;
            int rem = idx - cil * 324;
            int ly = rem / 18, lx = rem - (rem / 18) * 18;
            int ci = cg * 4 + cil;
            int gy = ty0 + ly - 1, gx = tx0 + lx - 1;
            float v = 0.0f;
            if (gy >= 0 && gy < PW && gx >= 0 && gx < PW) {
                float hv = h1[((b * 32 + ci) * PW + gy) * PW + gx];
                if (TANGENT) {
                    v = (hv > 0.0f) ? teps[(ci * PW + gy) * PW + gx] : 0.0f;
                } else {
                    v = hv;
                }
            }
            smem[cil][ly][lx] = v;
        }
        __syncthreads();
        #pragma unroll
        for (int cil = 0; cil < 4; cil++) {
            int ci = cg * 4 + cil;
            #pragma unroll
            for (int t9 = 0; t9 < 9; t9++) {
                float v = smem[cil][ty + t9 / 3][tx + t9 % 3];
                const float* wp = &w2t[(ci * 9 + t9) * 32 + half * 16];
                #pragma unroll
                for (int k = 0; k < 16; k++) acc[k] += v * wp[k];
            }
        }
    }
    const int py = ty0 + ty, px = tx0 + tx;
    #pragma unroll
    for (int k = 0; k < 16; k++) {
        int co = half * 16 + k;
        float r = acc[k];
        if (!TANGENT) r = fmaxf(r + b2[co], 0.0f);
        out[((b * 32 + co) * PW + py) * PW + px] = r;
    }
}

// ---------------- conv3 fused: y=conv(h2,w3)+b3, dy=conv((h2>0)?d2raw:0, w3)
// drift K = -c1*x - c2*y ; partial divergence S[b] += sum_c dy*eps
__global__ __launch_bounds__(256) void conv3_kernel(
    const float* __restrict__ h2, const float* __restrict__ d2raw,
    const float* __restrict__ xin, const float* __restrict__ epsin,
    const float* __restrict__ w3t, const float* __restrict__ b3,
    float* __restrict__ Kout, float* __restrict__ Sacc, float c1, float c2) {
    const int tile = blockIdx.x;
    const int b = blockIdx.y;
    const int ty0 = (tile / 10) * 16, tx0 = (tile % 10) * 16;
    const int tid = threadIdx.x;
    const int tx = tid & 15, ty = tid >> 4;
    __shared__ float sh[4][18][18];
    __shared__ float sd[4][18][18];
    __shared__ float wsum[4];
    float accy[3] = {0.0f, 0.0f, 0.0f};
    float accd[3] = {0.0f, 0.0f, 0.0f};
    for (int cg = 0; cg < 8; cg++) {
        __syncthreads();
        for (int idx = tid; idx < 4 * 324; idx += 256) {
            int cil = idx / 324;
            int rem = idx - cil * 324;
            int ly = rem / 18, lx = rem - (rem / 18) * 18;
            int ci = cg * 4 + cil;
            int gy = ty0 + ly - 1, gx = tx0 + lx - 1;
            float hv = 0.0f, dv = 0.0f;
            if (gy >= 0 && gy < PW && gx >= 0 && gx < PW) {
                int gi = ((b * 32 + ci) * PW + gy) * PW + gx;
                hv = h2[gi];
                float dr = d2raw[gi];
                dv = (hv > 0.0f) ? dr : 0.0f;
            }
            sh[cil][ly][lx] = hv;
            sd[cil][ly][lx] = dv;
        }
        __syncthreads();
        #pragma unroll
        for (int cil = 0; cil < 4; cil++) {
            int ci = cg * 4 + cil;
            #pragma unroll
            for (int t9 = 0; t9 < 9; t9++) {
                float vh = sh[cil][ty + t9 / 3][tx + t9 % 3];
                float vd = sd[cil][ty + t9 / 3][tx + t9 % 3];
                const float* wp = &w3t[(ci * 9 + t9) * 3];
                #pragma unroll
                for (int c = 0; c < 3; c++) {
                    accy[c] += vh * wp[c];
                    accd[c] += vd * wp[c];
                }
            }
        }
    }
    const int py = ty0 + ty, px = tx0 + tx;
    float s = 0.0f;
    #pragma unroll
    for (int c = 0; c < 3; c++) {
        int gi = ((b * 3 + c) * PW + py) * PW + px;
        float y = accy[c] + b3[c];
        Kout[gi] = -c1 * xin[gi] - c2 * y;
        float ev = epsin[(c * PW + py) * PW + px];
        s += accd[c] * ev;
    }
    #pragma unroll
    for (int off = 32; off > 0; off >>= 1) s += __shfl_down(s, off);
    if ((tid & 63) == 0) wsum[tid >> 6] = s;
    __syncthreads();
    if (tid == 0) atomicAdd(&Sacc[b], wsum[0] + wsum[1] + wsum[2] + wsum[3]);
}

// ---------------- RK4 pointwise stage update
__global__ void rk_pointwise(float* __restrict__ x0, float* __restrict__ xacc,
                             float* __restrict__ xst, const float* __restrict__ K,
                             int mode, float dt) {
    int i = blockIdx.x * 256 + threadIdx.x;
    if (i >= NX) return;
    float k = K[i];
    if (mode == 0) {
        xacc[i] = k;
        xst[i] = x0[i] + 0.5f * dt * k;
    } else if (mode == 1) {
        xacc[i] += 2.0f * k;
        xst[i] = x0[i] + 0.5f * dt * k;
    } else if (mode == 2) {
        xacc[i] += 2.0f * k;
        xst[i] = x0[i] + dt * k;
    } else {
        x0[i] += (dt / 6.0f) * (xacc[i] + k);
    }
}

// ---------------- sum z^2 per batch
__global__ void sumz2_kernel(const float* __restrict__ x0, float* __restrict__ sumz2) {
    int b = blockIdx.x, tid = threadIdx.x;
    __shared__ float wsum[4];
    float s = 0.0f;
    for (int i = tid; i < NDIM; i += 256) {
        float v = x0[b * NDIM + i];
        s += v * v;
    }
    #pragma unroll
    for (int off = 32; off > 0; off >>= 1) s += __shfl_down(s, off);
    if ((tid & 63) == 0) wsum[tid >> 6] = s;
    __syncthreads();
    if (tid == 0) sumz2[b] = wsum[0] + wsum[1] + wsum[2] + wsum[3];
}

// ---------------- final bpd
__global__ void bpd_kernel(const float* __restrict__ S, const float* __restrict__ sumz2,
                           float* __restrict__ out, MC40 mc) {
    int b = threadIdx.x;
    if (b >= NB) return;
    float lp = mc.A;
    for (int r = 0; r < 40; r++) lp -= mc.m[r] * S[r * 4 + b];
    float prior = -70574.479354f - 0.5f * sumz2[b];  // -0.5*Ndim*ln(2pi) - 0.5*sum z^2
    out[b] = -(prior + lp) * 1.8785164100960743e-5f; // * 1/(ln2*Ndim)
}

extern "C" void kernel_launch(void* const* d_in, const int* in_sizes, int n_in,
                              void* d_out, int out_size, void* d_ws, size_t ws_size,
                              hipStream_t stream) {
    const float* patches = (const float*)d_in[0];
    const float* epsin = (const float*)d_in[1];
    const float* w1 = (const float*)d_in[2];
    const float* b1 = (const float*)d_in[3];
    const float* wt = (const float*)d_in[4];
    const float* bt = (const float*)d_in[5];
    const float* w2 = (const float*)d_in[6];
    const float* b2 = (const float*)d_in[7];
    const float* w3 = (const float*)d_in[8];
    const float* b3 = (const float*)d_in[9];
    float* ws = (float*)d_ws;
    float* outp = (float*)d_out;

    // workspace layout (floats)
    float* Sbuf = ws + 0;              // 160
    float* sumz2 = ws + 160;           // 4
    float* emb = ws + 256;             // 40*32
    float* w1t = ws + 1536;            // 864
    float* w3t = ws + 2432;            // 864
    float* w2t = ws + 3328;            // 9216
    float* teps = ws + 12544;          // 32*PSQ = 819200
    float* h1 = ws + 831744;           // NB*32*PSQ = 3276800
    float* h2 = ws + 4108544;          // 3276800
    float* d2r = ws + 7385344;         // 3276800
    float* Kb = ws + 10662144;         // NX
    float* x0 = ws + 10969344;         // NX
    float* xacc = ws + 11276544;       // NX
    float* xst = ws + 11583744;        // NX  (total ~11.9M floats ~47.6MB)

    // host-side scalar schedule (double precision — avoids fp32 cancellation at t=eps)
    const double dt = (1.0 - 1e-5) / 10.0;
    TS40 ts;
    MC40 mc;
    float c1a[40], c2a[40];
    double A = 0.0;
    const double wgt[4] = {1.0, 2.0, 2.0, 1.0};
    for (int i = 0; i < 10; i++) {
        double t0 = 1e-5 + dt * i;
        double tr[4] = {t0, t0 + 0.5 * dt, t0 + 0.5 * dt, t0 + dt};
        for (int s = 0; s < 4; s++) {
            int r = i * 4 + s;
            double t = tr[s];
            double beta = 0.1 + 19.9 * t;
            double lmc = -0.25 * t * t * 19.9 - 0.05 * t;
            double stdv = 1.0 - exp(2.0 * lmc);
            double g2 = beta * (1.0 - exp(4.0 * lmc));
            double c2 = 0.5 * g2 / stdv;
            ts.t[r] = (float)t;
            c1a[r] = (float)(0.5 * beta);
            c2a[r] = (float)c2;
            double coef = dt / 6.0 * wgt[s];
            mc.m[r] = (float)(coef * c2);
            A += coef * (-0.5 * beta * (double)NDIM);
        }
    }
    mc.A = (float)A;

    hipMemsetAsync(Sbuf, 0, 164 * sizeof(float), stream);
    hipMemcpyAsync(x0, patches, NX * sizeof(float), hipMemcpyDeviceToDevice, stream);

    emb_kernel<<<40, 64, 0, stream>>>(wt, bt, emb, ts);
    repack_kernel<<<(32 * 3 * 9 + 255) / 256, 256, 0, stream>>>(w1, w1t, 32, 3);
    repack_kernel<<<(32 * 32 * 9 + 255) / 256, 256, 0, stream>>>(w2, w2t, 32, 32);
    repack_kernel<<<(3 * 32 * 9 + 255) / 256, 256, 0, stream>>>(w3, w3t, 3, 32);
    // teps = conv1(eps) — constant across all 40 rhs calls (eps is batch-broadcast)
    conv1_kernel<false><<<dim3(100, 1), 256, 0, stream>>>(epsin, w1t, nullptr, nullptr, teps);

    for (int i = 0; i < 10; i++) {
        for (int s = 0; s < 4; s++) {
            int r = i * 4 + s;
            const float* xin = (s == 0) ? x0 : xst;
            conv1_kernel<true><<<dim3(100, NB), 256, 0, stream>>>(xin, w1t, b1, emb + r * 32, h1);
            conv2_kernel<false><<<dim3(100, NB, 2), 256, 0, stream>>>(h1, teps, w2t, b2, h2);
            conv2_kernel<true><<<dim3(100, NB, 2), 256, 0, stream>>>(h1, teps, w2t, b2, d2r);
            conv3_kernel<<<dim3(100, NB), 256, 0, stream>>>(h2, d2r, xin, epsin, w3t, b3,
                                                            Kb, Sbuf + r * 4, c1a[r], c2a[r]);
            rk_pointwise<<<(NX + 255) / 256, 256, 0, stream>>>(x0, xacc, xst, Kb, s, (float)dt);
        }
    }
    sumz2_kernel<<<NB, 256, 0, stream>>>(x0, sumz2);
    bpd_kernel<<<1, 64, 0, stream>>>(Sbuf, sumz2, outp, mc);
}

// Round 2
// 1442.422 us; speedup vs baseline: 4.3603x; 4.3603x over previous
//
#include <hip/hip_runtime.h>
#include <math.h>

#define PW 160
#define PSQ 25600          // 160*160
#define NB 4
#define NX 307200          // NB*3*PSQ
#define NDIM 76800         // 3*PSQ

typedef __attribute__((ext_vector_type(8))) short short8;
typedef __attribute__((ext_vector_type(4))) float float4v;

struct TS40 { float t[40]; };
struct MC40 { float m[40]; float A; };

__device__ __forceinline__ unsigned short bf16s(float f) {
    unsigned u = __builtin_bit_cast(unsigned, f);
    return (unsigned short)((u + 0x7FFFu + ((u >> 16) & 1u)) >> 16);
}

// ---------------- time embedding
__global__ void emb_kernel(const float* __restrict__ wt, const float* __restrict__ bt,
                           float* __restrict__ emb, TS40 ts) {
    int r = blockIdx.x, k = threadIdx.x;   // 64 threads
    __shared__ float e64[64];
    float t = ts.t[r];
    int j = k & 31;
    float freq = expf(-0.29710775393471556f * (float)j);  // -ln(10000)/31
    float a = t * 999.0f * freq;
    e64[k] = (k < 32) ? sinf(a) : cosf(a);
    __syncthreads();
    if (k < 32) {
        float acc = bt[k];
        #pragma unroll 8
        for (int q = 0; q < 64; q++) acc += e64[q] * wt[q * 32 + k];
        emb[r * 32 + k] = acc;
    }
}

// ---------------- repack weights into MFMA A-fragment order (bf16)
// w2p[((tap*4+quad)*32+co)*8+j] = w2[co][quad*8+j][tap]
// w3p[((tap*4+quad)*16+co)*8+j] = co<3 ? w3[co][quad*8+j][tap] : 0
// w1p[(quad*32+co)*8+j]: k=quad*8+j = tap*3+ci, k<27 ? w1[co][ci][tap] : 0
__global__ void repack_kernel(const float* __restrict__ w1, const float* __restrict__ w2,
                              const float* __restrict__ w3, short* __restrict__ w1p,
                              short* __restrict__ w2p, short* __restrict__ w3p) {
    int tid = blockIdx.x * 256 + threadIdx.x;
    if (tid < 9216) {
        int j = tid & 7, co = (tid >> 3) & 31, q4 = tid >> 8;
        int tap = q4 >> 2, quad = q4 & 3, ci = quad * 8 + j;
        w2p[tid] = (short)bf16s(w2[(co * 32 + ci) * 9 + tap]);
    }
    if (tid < 4608) {
        int j = tid & 7, co = (tid >> 3) & 15, q4 = tid >> 7;
        int tap = q4 >> 2, quad = q4 & 3, ci = quad * 8 + j;
        float v = (co < 3) ? w3[(co * 32 + ci) * 9 + tap] : 0.0f;
        w3p[tid] = (short)bf16s(v);
    }
    if (tid < 1024) {
        int j = tid & 7, co = (tid >> 3) & 31, quad = tid >> 8;
        int k = quad * 8 + j;
        float v = 0.0f;
        if (k < 27) { int tap = (k * 11) >> 5; int ci = k - tap * 3; v = w1[(co * 3 + ci) * 9 + tap]; }
        w1p[tid] = (short)bf16s(v);
    }
}

// ---------------- conv1 (3->32) via MFMA, K=27 padded to 32.
// MODE 0: raw conv of eps -> tepsb (bf16 [pix][32])
// MODE 1: h1 = relu(conv+b1+emb) and d1 = (pre>0)?teps:0, both bf16 [b][pix][32]
template <int MODE>
__global__ __launch_bounds__(256) void conv1_mfma(
    const float* __restrict__ xin, const short* __restrict__ w1p,
    const float* __restrict__ b1, const float* __restrict__ embr,
    const short* __restrict__ tepsb, short* __restrict__ outH,
    short* __restrict__ outD) {
    const int tile = blockIdx.x, b = blockIdx.y;
    const int ty0 = (tile / 10) * 16, tx0 = (tile % 10) * 16;
    const int tid = threadIdx.x;
    const int lane = tid & 63, wv = tid >> 6;
    const int n = lane & 15, quad = lane >> 4;
    __shared__ float sX[3 * 324];
    __shared__ float sBE[32];
    if (MODE == 1 && tid < 32) sBE[tid] = b1[tid] + embr[tid];
    for (int idx = tid; idx < 3 * 324; idx += 256) {
        int ci = idx / 324, p = idx - ci * 324;
        int ly = p / 18, lx = p - ly * 18;
        int gy = ty0 + ly - 1, gx = tx0 + lx - 1;
        float v = 0.0f;
        if (gy >= 0 && gy < PW && gx >= 0 && gx < PW)
            v = xin[(size_t)(b * 3 + ci) * PSQ + gy * PW + gx];
        sX[idx] = v;
    }
    __syncthreads();
    int offj[8], valj[8];
    #pragma unroll
    for (int j = 0; j < 8; ++j) {
        int k = quad * 8 + j;
        valj[j] = (k < 27);
        int tap = (k * 11) >> 5; if (k >= 27) tap = 0;
        int ci = k - tap * 3;
        int dy = (tap * 11) >> 5;
        int dx = tap - dy * 3;
        offj[j] = ci * 324 + dy * 18 + dx + n;
    }
    short8 a0 = *(const short8*)&w1p[(quad * 32 + n) * 8];
    short8 a1 = *(const short8*)&w1p[(quad * 32 + 16 + n) * 8];
    float4v acc[4][2];
    #pragma unroll
    for (int r = 0; r < 4; ++r) {
        acc[r][0] = (float4v){0.f, 0.f, 0.f, 0.f};
        acc[r][1] = (float4v){0.f, 0.f, 0.f, 0.f};
    }
    #pragma unroll
    for (int r = 0; r < 4; ++r) {
        int row = wv * 4 + r;
        short8 bb;
        #pragma unroll
        for (int j = 0; j < 8; ++j) {
            float v = valj[j] ? sX[offj[j] + row * 18] : 0.0f;
            bb[j] = (short)bf16s(v);
        }
        acc[r][0] = __builtin_amdgcn_mfma_f32_16x16x32_bf16(a0, bb, acc[r][0], 0, 0, 0);
        acc[r][1] = __builtin_amdgcn_mfma_f32_16x16x32_bf16(a1, bb, acc[r][1], 0, 0, 0);
    }
    #pragma unroll
    for (int r = 0; r < 4; ++r) {
        int pix = (ty0 + wv * 4 + r) * PW + tx0 + n;
        #pragma unroll
        for (int mt = 0; mt < 2; ++mt) {
            int co0 = mt * 16 + quad * 4;
            size_t obase = (size_t)(b * PSQ + pix) * 32 + co0;
            if (MODE == 0) {
                uint2 hv;
                hv.x = (unsigned)bf16s(acc[r][mt][0]) | ((unsigned)bf16s(acc[r][mt][1]) << 16);
                hv.y = (unsigned)bf16s(acc[r][mt][2]) | ((unsigned)bf16s(acc[r][mt][3]) << 16);
                *(uint2*)&outH[obase] = hv;
            } else {
                uint2 t2 = *(const uint2*)&tepsb[(size_t)pix * 32 + co0];
                unsigned ts[4] = {t2.x & 0xFFFFu, t2.x >> 16, t2.y & 0xFFFFu, t2.y >> 16};
                unsigned hvp[4], dvp[4];
                #pragma unroll
                for (int g = 0; g < 4; ++g) {
                    float pre = acc[r][mt][g] + sBE[co0 + g];
                    hvp[g] = bf16s(fmaxf(pre, 0.0f));
                    dvp[g] = (pre > 0.0f) ? ts[g] : 0u;
                }
                uint2 hv, dv;
                hv.x = hvp[0] | (hvp[1] << 16); hv.y = hvp[2] | (hvp[3] << 16);
                dv.x = dvp[0] | (dvp[1] << 16); dv.y = dvp[2] | (dvp[3] << 16);
                *(uint2*)&outH[obase] = hv;
                *(uint2*)&outD[obase] = dv;
            }
        }
    }
}

// ---------------- conv2 fused primal+tangent (32->32), MFMA, relu-mask in epilogue
__global__ __launch_bounds__(256) void conv2_mfma(
    const short* __restrict__ h1g, const short* __restrict__ d1g,
    const short* __restrict__ w2p, const float* __restrict__ b2,
    short* __restrict__ h2g, short* __restrict__ d2g) {
    const int tile = blockIdx.x, b = blockIdx.y;
    const int ty0 = (tile / 10) * 16, tx0 = (tile % 10) * 16;
    const int tid = threadIdx.x;
    const int lane = tid & 63, wv = tid >> 6;
    const int n = lane & 15, quad = lane >> 4;
    __shared__ short sP[324 * 40];
    __shared__ short sD[324 * 40];
    __shared__ float sB2[32];
    if (tid < 32) sB2[tid] = b2[tid];
    const size_t bbase = (size_t)b * PSQ;
    for (int idx = tid; idx < 1296; idx += 256) {
        int p = idx >> 2, c4 = idx & 3;
        int ly = p / 18, lx = p - ly * 18;
        int gy = ty0 + ly - 1, gx = tx0 + lx - 1;
        uint4 vP = {0, 0, 0, 0}, vD = {0, 0, 0, 0};
        if (gy >= 0 && gy < PW && gx >= 0 && gx < PW) {
            size_t g = (bbase + gy * PW + gx) * 32;
            vP = ((const uint4*)(h1g + g))[c4];
            vD = ((const uint4*)(d1g + g))[c4];
        }
        *(uint4*)&sP[p * 40 + c4 * 8] = vP;
        *(uint4*)&sD[p * 40 + c4 * 8] = vD;
    }
    __syncthreads();
    float4v aP[4][2], aD[4][2];
    #pragma unroll
    for (int r = 0; r < 4; ++r) {
        aP[r][0] = (float4v){0.f, 0.f, 0.f, 0.f}; aP[r][1] = (float4v){0.f, 0.f, 0.f, 0.f};
        aD[r][0] = (float4v){0.f, 0.f, 0.f, 0.f}; aD[r][1] = (float4v){0.f, 0.f, 0.f, 0.f};
    }
    for (int ky = 0; ky < 3; ++ky) {
        for (int kx = 0; kx < 3; ++kx) {
            const int tap = ky * 3 + kx;
            short8 a0 = *(const short8*)&w2p[((tap * 4 + quad) * 32 + n) * 8];
            short8 a1 = *(const short8*)&w2p[((tap * 4 + quad) * 32 + 16 + n) * 8];
            #pragma unroll
            for (int r = 0; r < 4; ++r) {
                int p = (wv * 4 + r + ky) * 18 + n + kx;
                short8 bp = *(const short8*)&sP[p * 40 + quad * 8];
                short8 bd = *(const short8*)&sD[p * 40 + quad * 8];
                aP[r][0] = __builtin_amdgcn_mfma_f32_16x16x32_bf16(a0, bp, aP[r][0], 0, 0, 0);
                aP[r][1] = __builtin_amdgcn_mfma_f32_16x16x32_bf16(a1, bp, aP[r][1], 0, 0, 0);
                aD[r][0] = __builtin_amdgcn_mfma_f32_16x16x32_bf16(a0, bd, aD[r][0], 0, 0, 0);
                aD[r][1] = __builtin_amdgcn_mfma_f32_16x16x32_bf16(a1, bd, aD[r][1], 0, 0, 0);
            }
        }
    }
    #pragma unroll
    for (int r = 0; r < 4; ++r) {
        int pix = (ty0 + wv * 4 + r) * PW + tx0 + n;
        #pragma unroll
        for (int mt = 0; mt < 2; ++mt) {
            int co0 = mt * 16 + quad * 4;
            size_t obase = (size_t)(b * PSQ + pix) * 32 + co0;
            unsigned hvp[4], dvp[4];
            #pragma unroll
            for (int g = 0; g < 4; ++g) {
                float pre = aP[r][mt][g] + sB2[co0 + g];
                hvp[g] = bf16s(fmaxf(pre, 0.0f));
                dvp[g] = (pre > 0.0f) ? bf16s(aD[r][mt][g]) : 0u;
            }
            uint2 hv, dv;
            hv.x = hvp[0] | (hvp[1] << 16); hv.y = hvp[2] | (hvp[3] << 16);
            dv.x = dvp[0] | (dvp[1] << 16); dv.y = dvp[2] | (dvp[3] << 16);
            *(uint2*)&h2g[obase] = hv;
            *(uint2*)&d2g[obase] = dv;
        }
    }
}

// ---------------- conv3 fused (32->3) MFMA + drift + divergence partial sum
__global__ __launch_bounds__(256) void conv3_mfma(
    const short* __restrict__ h2g, const short* __restrict__ d2g,
    const short* __restrict__ w3p, const float* __restrict__ b3,
    const float* __restrict__ xin, const float* __restrict__ epsin,
    float* __restrict__ Kout, float* __restrict__ Sacc, float c1, float c2) {
    const int tile = blockIdx.x, b = blockIdx.y;
    const int ty0 = (tile / 10) * 16, tx0 = (tile % 10) * 16;
    const int tid = threadIdx.x;
    const int lane = tid & 63, wv = tid >> 6;
    const int n = lane & 15, quad = lane >> 4;
    __shared__ short sP[324 * 40];
    __shared__ short sD[324 * 40];
    __shared__ float wsum[4];
    const size_t bbase = (size_t)b * PSQ;
    for (int idx = tid; idx < 1296; idx += 256) {
        int p = idx >> 2, c4 = idx & 3;
        int ly = p / 18, lx = p - ly * 18;
        int gy = ty0 + ly - 1, gx = tx0 + lx - 1;
        uint4 vP = {0, 0, 0, 0}, vD = {0, 0, 0, 0};
        if (gy >= 0 && gy < PW && gx >= 0 && gx < PW) {
            size_t g = (bbase + gy * PW + gx) * 32;
            vP = ((const uint4*)(h2g + g))[c4];
            vD = ((const uint4*)(d2g + g))[c4];
        }
        *(uint4*)&sP[p * 40 + c4 * 8] = vP;
        *(uint4*)&sD[p * 40 + c4 * 8] = vD;
    }
    __syncthreads();
    float4v aP[4], aD[4];
    #pragma unroll
    for (int r = 0; r < 4; ++r) {
        aP[r] = (float4v){0.f, 0.f, 0.f, 0.f};
        aD[r] = (float4v){0.f, 0.f, 0.f, 0.f};
    }
    for (int ky = 0; ky < 3; ++ky) {
        for (int kx = 0; kx < 3; ++kx) {
            const int tap = ky * 3 + kx;
            short8 a0 = *(const short8*)&w3p[((tap * 4 + quad) * 16 + n) * 8];
            #pragma unroll
            for (int r = 0; r < 4; ++r) {
                int p = (wv * 4 + r + ky) * 18 + n + kx;
                short8 bp = *(const short8*)&sP[p * 40 + quad * 8];
                short8 bd = *(const short8*)&sD[p * 40 + quad * 8];
                aP[r] = __builtin_amdgcn_mfma_f32_16x16x32_bf16(a0, bp, aP[r], 0, 0, 0);
                aD[r] = __builtin_amdgcn_mfma_f32_16x16x32_bf16(a0, bd, aD[r], 0, 0, 0);
            }
        }
    }
    float s = 0.0f;
    #pragma unroll
    for (int r = 0; r < 4; ++r) {
        int pix = (ty0 + wv * 4 + r) * PW + tx0 + n;
        if (quad == 0) {
            #pragma unroll
            for (int c = 0; c < 3; ++c) {
                float y = aP[r][c] + b3[c];
                size_t gi = (size_t)(b * 3 + c) * PSQ + pix;
                Kout[gi] = -c1 * xin[gi] - c2 * y;
                s += aD[r][c] * epsin[c * PSQ + pix];
            }
        }
    }
    #pragma unroll
    for (int off = 32; off > 0; off >>= 1) s += __shfl_down(s, off);
    if (lane == 0) wsum[wv] = s;
    __syncthreads();
    if (tid == 0) atomicAdd(&Sacc[b], wsum[0] + wsum[1] + wsum[2] + wsum[3]);
}

// ---------------- RK4 pointwise stage update (float4)
__global__ void rk_pointwise(float4* __restrict__ x0, float4* __restrict__ xacc,
                             float4* __restrict__ xst, const float4* __restrict__ K,
                             int mode, float dt) {
    int i = blockIdx.x * 256 + threadIdx.x;  // 300*256 = 76800 float4s exactly
    float4 k = K[i];
    if (mode == 0) {
        xacc[i] = k;
        float4 x = x0[i];
        float4 o; o.x = x.x + 0.5f * dt * k.x; o.y = x.y + 0.5f * dt * k.y;
        o.z = x.z + 0.5f * dt * k.z; o.w = x.w + 0.5f * dt * k.w;
        xst[i] = o;
    } else if (mode == 1) {
        float4 a = xacc[i];
        a.x += 2.0f * k.x; a.y += 2.0f * k.y; a.z += 2.0f * k.z; a.w += 2.0f * k.w;
        xacc[i] = a;
        float4 x = x0[i];
        float4 o; o.x = x.x + 0.5f * dt * k.x; o.y = x.y + 0.5f * dt * k.y;
        o.z = x.z + 0.5f * dt * k.z; o.w = x.w + 0.5f * dt * k.w;
        xst[i] = o;
    } else if (mode == 2) {
        float4 a = xacc[i];
        a.x += 2.0f * k.x; a.y += 2.0f * k.y; a.z += 2.0f * k.z; a.w += 2.0f * k.w;
        xacc[i] = a;
        float4 x = x0[i];
        float4 o; o.x = x.x + dt * k.x; o.y = x.y + dt * k.y;
        o.z = x.z + dt * k.z; o.w = x.w + dt * k.w;
        xst[i] = o;
    } else {
        float4 a = xacc[i];
        float4 x = x0[i];
        float c = dt / 6.0f;
        x.x += c * (a.x + k.x); x.y += c * (a.y + k.y);
        x.z += c * (a.z + k.z); x.w += c * (a.w + k.w);
        x0[i] = x;
    }
}

// ---------------- sum z^2 per batch (parallel over 25 segments)
__global__ void sumz2_kernel(const float* __restrict__ x0, float* __restrict__ sumz2) {
    int b = blockIdx.x, seg = blockIdx.y, tid = threadIdx.x;
    const float* p = x0 + (size_t)b * NDIM + seg * 3072;
    float s = 0.0f;
    for (int i = tid; i < 3072; i += 256) { float v = p[i]; s += v * v; }
    #pragma unroll
    for (int off = 32; off > 0; off >>= 1) s += __shfl_down(s, off);
    __shared__ float wsum[4];
    if ((tid & 63) == 0) wsum[tid >> 6] = s;
    __syncthreads();
    if (tid == 0) atomicAdd(&sumz2[b], wsum[0] + wsum[1] + wsum[2] + wsum[3]);
}

// ---------------- final bpd
__global__ void bpd_kernel(const float* __restrict__ S, const float* __restrict__ sumz2,
                           float* __restrict__ out, MC40 mc) {
    int b = threadIdx.x;
    if (b >= NB) return;
    float lp = mc.A;
    for (int r = 0; r < 40; r++) lp -= mc.m[r] * S[r * 4 + b];
    float prior = -70574.479354f - 0.5f * sumz2[b];
    out[b] = -(prior + lp) * 1.8785164100960743e-5f;
}

extern "C" void kernel_launch(void* const* d_in, const int* in_sizes, int n_in,
                              void* d_out, int out_size, void* d_ws, size_t ws_size,
                              hipStream_t stream) {
    const float* patches = (const float*)d_in[0];
    const float* epsin = (const float*)d_in[1];
    const float* w1 = (const float*)d_in[2];
    const float* b1 = (const float*)d_in[3];
    const float* wt = (const float*)d_in[4];
    const float* bt = (const float*)d_in[5];
    const float* w2 = (const float*)d_in[6];
    const float* b2 = (const float*)d_in[7];
    const float* w3 = (const float*)d_in[8];
    const float* b3 = (const float*)d_in[9];
    float* outp = (float*)d_out;
    char* wsb = (char*)d_ws;

    float* Sbuf  = (float*)(wsb + 0);          // 160 f
    float* sumz2 = (float*)(wsb + 640);        // 4 f
    float* emb   = (float*)(wsb + 1024);       // 1280 f
    short* w1p   = (short*)(wsb + 6144);       // 1024 bf16
    short* w2p   = (short*)(wsb + 8192);       // 9216 bf16
    short* w3p   = (short*)(wsb + 26624);      // 4608 bf16
    short* tepsb = (short*)(wsb + 36864);      // 819200 bf16
    short* h1g   = (short*)(wsb + 1675264);    // 3276800 bf16
    short* d1g   = (short*)(wsb + 8228864);
    short* h2g   = (short*)(wsb + 14782464);
    short* d2g   = (short*)(wsb + 21336064);
    float* Kb    = (float*)(wsb + 27889664);   // NX f
    float* x0    = (float*)(wsb + 29118464);
    float* xacc  = (float*)(wsb + 30347264);
    float* xst   = (float*)(wsb + 31576064);   // end ~32.8 MB

    // host-side scalar schedule in double
    const double dt = (1.0 - 1e-5) / 10.0;
    TS40 ts; MC40 mc;
    float c1a[40], c2a[40];
    double A = 0.0;
    const double wgt[4] = {1.0, 2.0, 2.0, 1.0};
    for (int i = 0; i < 10; i++) {
        double t0 = 1e-5 + dt * i;
        double tr[4] = {t0, t0 + 0.5 * dt, t0 + 0.5 * dt, t0 + dt};
        for (int s = 0; s < 4; s++) {
            int r = i * 4 + s;
            double t = tr[s];
            double beta = 0.1 + 19.9 * t;
            double lmc = -0.25 * t * t * 19.9 - 0.05 * t;
            double stdv = 1.0 - exp(2.0 * lmc);
            double g2 = beta * (1.0 - exp(4.0 * lmc));
            double c2 = 0.5 * g2 / stdv;
            ts.t[r] = (float)t;
            c1a[r] = (float)(0.5 * beta);
            c2a[r] = (float)c2;
            double coef = dt / 6.0 * wgt[s];
            mc.m[r] = (float)(coef * c2);
            A += coef * (-0.5 * beta * (double)NDIM);
        }
    }
    mc.A = (float)A;

    hipMemsetAsync(wsb, 0, 656, stream);  // Sbuf + sumz2
    hipMemcpyAsync(x0, patches, NX * sizeof(float), hipMemcpyDeviceToDevice, stream);

    emb_kernel<<<40, 64, 0, stream>>>(wt, bt, emb, ts);
    repack_kernel<<<36, 256, 0, stream>>>(w1, w2, w3, w1p, w2p, w3p);
    conv1_mfma<0><<<dim3(100, 1), 256, 0, stream>>>(epsin, w1p, nullptr, nullptr, nullptr,
                                                    tepsb, nullptr);
    for (int i = 0; i < 10; i++) {
        for (int s = 0; s < 4; s++) {
            int r = i * 4 + s;
            const float* xin = (s == 0) ? x0 : xst;
            conv1_mfma<1><<<dim3(100, NB), 256, 0, stream>>>(xin, w1p, b1, emb + r * 32,
                                                             tepsb, h1g, d1g);
            conv2_mfma<<<dim3(100, NB), 256, 0, stream>>>(h1g, d1g, w2p, b2, h2g, d2g);
            conv3_mfma<<<dim3(100, NB), 256, 0, stream>>>(h2g, d2g, w3p, b3, xin, epsin,
                                                          Kb, Sbuf + r * 4, c1a[r], c2a[r]);
            rk_pointwise<<<300, 256, 0, stream>>>((float4*)x0, (float4*)xacc, (float4*)xst,
                                                  (const float4*)Kb, s, (float)dt);
        }
    }
    sumz2_kernel<<<dim3(NB, 25), 256, 0, stream>>>(x0, sumz2);
    bpd_kernel<<<1, 64, 0, stream>>>(Sbuf, sumz2, outp, mc);
}

// Round 3
// 1349.531 us; speedup vs baseline: 4.6604x; 1.0688x over previous
//
#include <hip/hip_runtime.h>
#include <math.h>

#define PW 160
#define PSQ 25600          // 160*160
#define NB 4
#define NX 307200          // NB*3*PSQ
#define NDIM 76800         // 3*PSQ

typedef __attribute__((ext_vector_type(8))) short short8;
typedef __attribute__((ext_vector_type(4))) float float4v;

struct TS40 { float t[40]; };
struct MC40 { float m[40]; float A; };

__device__ __forceinline__ unsigned short bf16s(float f) {
    unsigned u = __builtin_bit_cast(unsigned, f);
    return (unsigned short)((u + 0x7FFFu + ((u >> 16) & 1u)) >> 16);
}
__device__ __forceinline__ unsigned packbf(float a, float b) {
    return (unsigned)bf16s(a) | ((unsigned)bf16s(b) << 16);
}

// ---------------- time embedding
__global__ void emb_kernel(const float* __restrict__ wt, const float* __restrict__ bt,
                           float* __restrict__ emb, TS40 ts) {
    int r = blockIdx.x, k = threadIdx.x;   // 64 threads
    __shared__ float e64[64];
    float t = ts.t[r];
    int j = k & 31;
    float freq = expf(-0.29710775393471556f * (float)j);  // -ln(10000)/31
    float a = t * 999.0f * freq;
    e64[k] = (k < 32) ? sinf(a) : cosf(a);
    __syncthreads();
    if (k < 32) {
        float acc = bt[k];
        #pragma unroll 8
        for (int q = 0; q < 64; q++) acc += e64[q] * wt[q * 32 + k];
        emb[r * 32 + k] = acc;
    }
}

// ---------------- repack weights into MFMA A-fragment order (bf16)
__global__ void repack_kernel(const float* __restrict__ w1, const float* __restrict__ w2,
                              const float* __restrict__ w3, short* __restrict__ w1p,
                              short* __restrict__ w2p, short* __restrict__ w3p) {
    int tid = blockIdx.x * 256 + threadIdx.x;
    if (tid < 9216) {
        int j = tid & 7, co = (tid >> 3) & 31, q4 = tid >> 8;
        int tap = q4 >> 2, quad = q4 & 3, ci = quad * 8 + j;
        w2p[tid] = (short)bf16s(w2[(co * 32 + ci) * 9 + tap]);
    }
    if (tid < 4608) {
        int j = tid & 7, co = (tid >> 3) & 15, q4 = tid >> 7;
        int tap = q4 >> 2, quad = q4 & 3, ci = quad * 8 + j;
        float v = (co < 3) ? w3[(co * 32 + ci) * 9 + tap] : 0.0f;
        w3p[tid] = (short)bf16s(v);
    }
    if (tid < 1024) {
        int j = tid & 7, co = (tid >> 3) & 31, quad = tid >> 8;
        int k = quad * 8 + j;
        float v = 0.0f;
        if (k < 27) { int tap = (k * 11) >> 5; int ci = k - tap * 3; v = w1[(co * 3 + ci) * 9 + tap]; }
        w1p[tid] = (short)bf16s(v);
    }
}

// ---------------- teps = raw conv1(eps), full image, bf16 [pix][32]
__global__ __launch_bounds__(256) void teps_conv1(
    const float* __restrict__ xin, const short* __restrict__ w1p,
    short* __restrict__ outH) {
    const int tile = blockIdx.x;
    const int ty0 = (tile / 10) * 16, tx0 = (tile % 10) * 16;
    const int tid = threadIdx.x;
    const int lane = tid & 63, wv = tid >> 6;
    const int n = lane & 15, quad = lane >> 4;
    __shared__ float sX[3 * 324];
    for (int idx = tid; idx < 3 * 324; idx += 256) {
        int ci = idx / 324, p = idx - ci * 324;
        int ly = p / 18, lx = p - ly * 18;
        int gy = ty0 + ly - 1, gx = tx0 + lx - 1;
        float v = 0.0f;
        if (gy >= 0 && gy < PW && gx >= 0 && gx < PW)
            v = xin[(size_t)ci * PSQ + gy * PW + gx];
        sX[idx] = v;
    }
    __syncthreads();
    int offj[8], valj[8];
    #pragma unroll
    for (int j = 0; j < 8; ++j) {
        int k = quad * 8 + j;
        valj[j] = (k < 27);
        int tap = (k * 11) >> 5; if (k >= 27) tap = 0;
        int ci = k - tap * 3;
        int dy = (tap * 11) >> 5, dx = tap - dy * 3;
        offj[j] = ci * 324 + dy * 18 + dx + n;
    }
    short8 a0 = *(const short8*)&w1p[(quad * 32 + n) * 8];
    short8 a1 = *(const short8*)&w1p[(quad * 32 + 16 + n) * 8];
    #pragma unroll
    for (int r = 0; r < 4; ++r) {
        int row = wv * 4 + r;
        short8 bb;
        #pragma unroll
        for (int j = 0; j < 8; ++j) {
            float v = valj[j] ? sX[offj[j] + row * 18] : 0.0f;
            bb[j] = (short)bf16s(v);
        }
        float4v acc0 = {0.f, 0.f, 0.f, 0.f}, acc1 = {0.f, 0.f, 0.f, 0.f};
        acc0 = __builtin_amdgcn_mfma_f32_16x16x32_bf16(a0, bb, acc0, 0, 0, 0);
        acc1 = __builtin_amdgcn_mfma_f32_16x16x32_bf16(a1, bb, acc1, 0, 0, 0);
        int pix = (ty0 + row) * PW + tx0 + n;
        uint2 h0, h1v;
        h0.x = packbf(acc0[0], acc0[1]); h0.y = packbf(acc0[2], acc0[3]);
        h1v.x = packbf(acc1[0], acc1[1]); h1v.y = packbf(acc1[2], acc1[3]);
        *(uint2*)&outH[(size_t)pix * 32 + quad * 4] = h0;
        *(uint2*)&outH[(size_t)pix * 32 + 16 + quad * 4] = h1v;
    }
}

// ---------------- fully fused RK stage: conv1+conv2+conv3+divergence+RK update
// tile 8x16 out; regions: x 14x22, h1 12x20 (240px), h2 10x18 (180px)
__global__ __launch_bounds__(256, 2) void fused_stage(
    const float* __restrict__ xin, float* __restrict__ x0,
    float* __restrict__ xacc, float* __restrict__ xst,
    const short* __restrict__ w1p, const short* __restrict__ w2p,
    const short* __restrict__ w3p, const float* __restrict__ b1,
    const float* __restrict__ b2, const float* __restrict__ b3,
    const float* __restrict__ embr, const short* __restrict__ tepsb,
    const float* __restrict__ epsin, float* __restrict__ Sacc,
    float c1, float c2, float dt, int mode) {
    const int tile = blockIdx.x;            // 0..199
    const int b = blockIdx.y;
    const int oy = (tile / 10) * 8, ox = (tile % 10) * 16;
    const int tid = threadIdx.x;
    const int lane = tid & 63, wv = tid >> 6;
    const int n = lane & 15, quad = lane >> 4;

    __shared__ float sX[3 * 308];           // 14x22 x-tile, fp32
    __shared__ float sBE[32], sB2[32], sB3[4];
    __shared__ short sH1[240 * 40], sD1[240 * 40];
    __shared__ short sH2[180 * 40], sD2[180 * 40];
    __shared__ float wsum[4];

    if (tid < 32) { sBE[tid] = b1[tid] + embr[tid]; sB2[tid] = b2[tid]; }
    if (tid < 3) sB3[tid] = b3[tid];

    // ---- stage x region (zero-padded outside image)
    for (int idx = tid; idx < 3 * 308; idx += 256) {
        int ci = idx / 308, p = idx - ci * 308;
        int ly = p / 22, lx = p - ly * 22;
        int gy = oy - 3 + ly, gx = ox - 3 + lx;
        float v = 0.0f;
        if (gy >= 0 && gy < PW && gx >= 0 && gx < PW)
            v = xin[(size_t)(b * 3 + ci) * PSQ + gy * PW + gx];
        sX[idx] = v;
    }
    __syncthreads();

    // ---- phase 1: conv1 over h1 region (240 px, 15 n-tiles)
    {
        int koff[8], kval[8];
        #pragma unroll
        for (int j = 0; j < 8; ++j) {
            int k = quad * 8 + j;
            kval[j] = (k < 27);
            int tap = (k * 11) >> 5; if (k >= 27) tap = 0;
            int ci = k - tap * 3;
            int dy = (tap * 11) >> 5, dx = tap - dy * 3;
            koff[j] = ci * 308 + dy * 22 + dx;
        }
        short8 a0 = *(const short8*)&w1p[(quad * 32 + n) * 8];
        short8 a1 = *(const short8*)&w1p[(quad * 32 + 16 + n) * 8];
        for (int t = wv; t < 15; t += 4) {
            int p = t * 16 + n;                // < 240 always
            int ry = p / 20, rx = p - ry * 20;
            int base = ry * 22 + rx;
            short8 bb;
            #pragma unroll
            for (int j = 0; j < 8; ++j) {
                float v = kval[j] ? sX[koff[j] + base] : 0.0f;
                bb[j] = (short)bf16s(v);
            }
            float4v acc0 = {0.f, 0.f, 0.f, 0.f}, acc1 = {0.f, 0.f, 0.f, 0.f};
            acc0 = __builtin_amdgcn_mfma_f32_16x16x32_bf16(a0, bb, acc0, 0, 0, 0);
            acc1 = __builtin_amdgcn_mfma_f32_16x16x32_bf16(a1, bb, acc1, 0, 0, 0);
            int gy = oy - 2 + ry, gx = ox - 2 + rx;
            int inimg = (gy >= 0 && gy < PW && gx >= 0 && gx < PW);
            size_t tbase = inimg ? ((size_t)(gy * PW + gx) * 32) : 0;
            #pragma unroll
            for (int mt = 0; mt < 2; ++mt) {
                float4v* ac = mt ? &acc1 : &acc0;
                int co0 = mt * 16 + quad * 4;
                uint2 t2 = {0, 0};
                if (inimg) t2 = *(const uint2*)&tepsb[tbase + co0];
                unsigned ts4[4] = {t2.x & 0xFFFFu, t2.x >> 16, t2.y & 0xFFFFu, t2.y >> 16};
                unsigned hv[4], dv[4];
                #pragma unroll
                for (int g = 0; g < 4; ++g) {
                    float pre = (*ac)[g] + sBE[co0 + g];
                    hv[g] = inimg ? (unsigned)bf16s(fmaxf(pre, 0.0f)) : 0u;
                    dv[g] = (inimg && pre > 0.0f) ? ts4[g] : 0u;
                }
                uint2 hw, dw;
                hw.x = hv[0] | (hv[1] << 16); hw.y = hv[2] | (hv[3] << 16);
                dw.x = dv[0] | (dv[1] << 16); dw.y = dv[2] | (dv[3] << 16);
                *(uint2*)&sH1[p * 40 + co0] = hw;
                *(uint2*)&sD1[p * 40 + co0] = dw;
            }
        }
    }
    __syncthreads();

    // ---- phase 2: conv2 over h2 region (180 px, 12 n-tiles)
    {
        short8 a2[9][2];
        #pragma unroll
        for (int tap = 0; tap < 9; ++tap) {
            a2[tap][0] = *(const short8*)&w2p[((tap * 4 + quad) * 32 + n) * 8];
            a2[tap][1] = *(const short8*)&w2p[((tap * 4 + quad) * 32 + 16 + n) * 8];
        }
        for (int ti = 0; ti < 3; ++ti) {
            int t = wv * 3 + ti;
            int p = t * 16 + n;
            int pc = p < 180 ? p : 179;
            int ry = pc / 18, rx = pc - ry * 18;
            float4v aP0 = {0.f,0.f,0.f,0.f}, aP1 = {0.f,0.f,0.f,0.f};
            float4v aD0 = {0.f,0.f,0.f,0.f}, aD1 = {0.f,0.f,0.f,0.f};
            #pragma unroll
            for (int tap = 0; tap < 9; ++tap) {
                int dy = (tap * 11) >> 5, dx = tap - dy * 3;
                int q = (ry + dy) * 20 + rx + dx;
                short8 bp = *(const short8*)&sH1[q * 40 + quad * 8];
                short8 bd = *(const short8*)&sD1[q * 40 + quad * 8];
                aP0 = __builtin_amdgcn_mfma_f32_16x16x32_bf16(a2[tap][0], bp, aP0, 0, 0, 0);
                aP1 = __builtin_amdgcn_mfma_f32_16x16x32_bf16(a2[tap][1], bp, aP1, 0, 0, 0);
                aD0 = __builtin_amdgcn_mfma_f32_16x16x32_bf16(a2[tap][0], bd, aD0, 0, 0, 0);
                aD1 = __builtin_amdgcn_mfma_f32_16x16x32_bf16(a2[tap][1], bd, aD1, 0, 0, 0);
            }
            int gy = oy - 1 + ry, gx = ox - 1 + rx;
            int inimg = (gy >= 0 && gy < PW && gx >= 0 && gx < PW);
            if (p < 180) {
                #pragma unroll
                for (int mt = 0; mt < 2; ++mt) {
                    float4v* acP = mt ? &aP1 : &aP0;
                    float4v* acD = mt ? &aD1 : &aD0;
                    int co0 = mt * 16 + quad * 4;
                    unsigned hv[4], dv[4];
                    #pragma unroll
                    for (int g = 0; g < 4; ++g) {
                        float pre = (*acP)[g] + sB2[co0 + g];
                        hv[g] = inimg ? (unsigned)bf16s(fmaxf(pre, 0.0f)) : 0u;
                        dv[g] = (inimg && pre > 0.0f) ? (unsigned)bf16s((*acD)[g]) : 0u;
                    }
                    uint2 hw, dw;
                    hw.x = hv[0] | (hv[1] << 16); hw.y = hv[2] | (hv[3] << 16);
                    dw.x = dv[0] | (dv[1] << 16); dw.y = dv[2] | (dv[3] << 16);
                    *(uint2*)&sH2[p * 40 + co0] = hw;
                    *(uint2*)&sD2[p * 40 + co0] = dw;
                }
            }
        }
    }
    __syncthreads();

    // ---- phase 3: conv3 over out tile (128 px, 8 n-tiles) + drift + divergence + RK
    float s = 0.0f;
    {
        short8 a3[9];
        #pragma unroll
        for (int tap = 0; tap < 9; ++tap)
            a3[tap] = *(const short8*)&w3p[((tap * 4 + quad) * 16 + n) * 8];
        for (int ti = 0; ti < 2; ++ti) {
            int t = wv * 2 + ti;              // 0..7 = output row
            int ry = t, rx = n;
            float4v aP = {0.f,0.f,0.f,0.f}, aD = {0.f,0.f,0.f,0.f};
            #pragma unroll
            for (int tap = 0; tap < 9; ++tap) {
                int dy = (tap * 11) >> 5, dx = tap - dy * 3;
                int q = (ry + dy) * 18 + rx + dx;
                short8 bp = *(const short8*)&sH2[q * 40 + quad * 8];
                short8 bd = *(const short8*)&sD2[q * 40 + quad * 8];
                aP = __builtin_amdgcn_mfma_f32_16x16x32_bf16(a3[tap], bp, aP, 0, 0, 0);
                aD = __builtin_amdgcn_mfma_f32_16x16x32_bf16(a3[tap], bd, aD, 0, 0, 0);
            }
            if (quad == 0) {
                int gy = oy + ry, gx = ox + rx;
                int pix = gy * PW + gx;
                #pragma unroll
                for (int c = 0; c < 3; ++c) {
                    float y = aP[c] + sB3[c];
                    float xv = sX[c * 308 + (ry + 3) * 22 + (rx + 3)];
                    float k = -c1 * xv - c2 * y;
                    size_t gi = (size_t)(b * 3 + c) * PSQ + pix;
                    if (mode == 0) {
                        xacc[gi] = k;
                        xst[gi] = xv + 0.5f * dt * k;     // xin == x0 at stage 0
                    } else if (mode == 1) {
                        xacc[gi] += 2.0f * k;
                        xst[gi] = x0[gi] + 0.5f * dt * k;
                    } else if (mode == 2) {
                        xacc[gi] += 2.0f * k;
                        xst[gi] = x0[gi] + dt * k;
                    } else {
                        x0[gi] += (dt / 6.0f) * (xacc[gi] + k);
                    }
                    s += aD[c] * epsin[c * PSQ + pix];
                }
            }
        }
    }
    #pragma unroll
    for (int off = 32; off > 0; off >>= 1) s += __shfl_down(s, off);
    if (lane == 0) wsum[wv] = s;
    __syncthreads();
    if (tid == 0) atomicAdd(&Sacc[b], wsum[0] + wsum[1] + wsum[2] + wsum[3]);
}

// ---------------- sum z^2 per batch (parallel over 25 segments)
__global__ void sumz2_kernel(const float* __restrict__ x0, float* __restrict__ sumz2) {
    int b = blockIdx.x, seg = blockIdx.y, tid = threadIdx.x;
    const float* p = x0 + (size_t)b * NDIM + seg * 3072;
    float s = 0.0f;
    for (int i = tid; i < 3072; i += 256) { float v = p[i]; s += v * v; }
    #pragma unroll
    for (int off = 32; off > 0; off >>= 1) s += __shfl_down(s, off);
    __shared__ float wsum[4];
    if ((tid & 63) == 0) wsum[tid >> 6] = s;
    __syncthreads();
    if (tid == 0) atomicAdd(&sumz2[b], wsum[0] + wsum[1] + wsum[2] + wsum[3]);
}

// ---------------- final bpd
__global__ void bpd_kernel(const float* __restrict__ S, const float* __restrict__ sumz2,
                           float* __restrict__ out, MC40 mc) {
    int b = threadIdx.x;
    if (b >= NB) return;
    float lp = mc.A;
    for (int r = 0; r < 40; r++) lp -= mc.m[r] * S[r * 4 + b];
    float prior = -70574.479354f - 0.5f * sumz2[b];
    out[b] = -(prior + lp) * 1.8785164100960743e-5f;
}

extern "C" void kernel_launch(void* const* d_in, const int* in_sizes, int n_in,
                              void* d_out, int out_size, void* d_ws, size_t ws_size,
                              hipStream_t stream) {
    const float* patches = (const float*)d_in[0];
    const float* epsin = (const float*)d_in[1];
    const float* w1 = (const float*)d_in[2];
    const float* b1 = (const float*)d_in[3];
    const float* wt = (const float*)d_in[4];
    const float* bt = (const float*)d_in[5];
    const float* w2 = (const float*)d_in[6];
    const float* b2 = (const float*)d_in[7];
    const float* w3 = (const float*)d_in[8];
    const float* b3 = (const float*)d_in[9];
    float* outp = (float*)d_out;
    char* wsb = (char*)d_ws;

    float* Sbuf  = (float*)(wsb + 0);          // 160 f
    float* sumz2 = (float*)(wsb + 640);        // 4 f
    float* emb   = (float*)(wsb + 1024);       // 1280 f
    short* w1p   = (short*)(wsb + 6144);       // 1024 bf16
    short* w2p   = (short*)(wsb + 8192);       // 9216 bf16
    short* w3p   = (short*)(wsb + 26624);      // 4608 bf16
    short* tepsb = (short*)(wsb + 36864);      // 819200 bf16
    float* x0    = (float*)(wsb + 1675264);    // NX f
    float* xacc  = (float*)(wsb + 2904064);
    float* xst   = (float*)(wsb + 4132864);    // end ~5.4 MB

    const double dt = (1.0 - 1e-5) / 10.0;
    TS40 ts; MC40 mc;
    float c1a[40], c2a[40];
    double A = 0.0;
    const double wgt[4] = {1.0, 2.0, 2.0, 1.0};
    for (int i = 0; i < 10; i++) {
        double t0 = 1e-5 + dt * i;
        double tr[4] = {t0, t0 + 0.5 * dt, t0 + 0.5 * dt, t0 + dt};
        for (int s = 0; s < 4; s++) {
            int r = i * 4 + s;
            double t = tr[s];
            double beta = 0.1 + 19.9 * t;
            double lmc = -0.25 * t * t * 19.9 - 0.05 * t;
            double stdv = 1.0 - exp(2.0 * lmc);
            double g2 = beta * (1.0 - exp(4.0 * lmc));
            double c2 = 0.5 * g2 / stdv;
            ts.t[r] = (float)t;
            c1a[r] = (float)(0.5 * beta);
            c2a[r] = (float)c2;
            double coef = dt / 6.0 * wgt[s];
            mc.m[r] = (float)(coef * c2);
            A += coef * (-0.5 * beta * (double)NDIM);
        }
    }
    mc.A = (float)A;

    hipMemsetAsync(wsb, 0, 656, stream);  // Sbuf + sumz2
    hipMemcpyAsync(x0, patches, NX * sizeof(float), hipMemcpyDeviceToDevice, stream);

    emb_kernel<<<40, 64, 0, stream>>>(wt, bt, emb, ts);
    repack_kernel<<<36, 256, 0, stream>>>(w1, w2, w3, w1p, w2p, w3p);
    teps_conv1<<<100, 256, 0, stream>>>(epsin, w1p, tepsb);

    for (int i = 0; i < 10; i++) {
        for (int s = 0; s < 4; s++) {
            int r = i * 4 + s;
            const float* xin = (s == 0) ? x0 : xst;
            fused_stage<<<dim3(200, NB), 256, 0, stream>>>(
                xin, x0, xacc, xst, w1p, w2p, w3p, b1, b2, b3,
                emb + r * 32, tepsb, epsin, Sbuf + r * 4,
                c1a[r], c2a[r], (float)dt, s);
        }
    }
    sumz2_kernel<<<dim3(NB, 25), 256, 0, stream>>>(x0, sumz2);
    bpd_kernel<<<1, 64, 0, stream>>>(Sbuf, sumz2, outp, mc);
}